// Round 7
// baseline (270.315 us; speedup 1.0000x reference)
//
// PatchSampleF R6 = R3 with B-staging index bug fixed (LDS overflow crash).
// Bug was: nB=tid>>2 & rows nB+128r -> rows up to 511 in a 256-row LDS tile.
// Now: nB=tid>>3 (0..63), c8=tid&7, rows nB+64r (r=0..3) -> exactly 256 rows.
// Dense GEMM1 with register-4x4-transpose A staging, bf16 weight pre-conversion,
// T14 issue-early/write-late staging in both GEMMs.
//   k0_prep: w1,w2 fp32 -> bf16 (in d_ws, once per call)
//   k1_dense: h[b*4096+hw, n] = relu(feat[b,:,hw].w1[n,:]+b1) for ALL hw
//   k2_gather: gather h rows by patch_id, GEMM2 + bias + L2-normalize -> out
// MFMA 16x16x32_bf16; C/D: col=lane&15, row=(lane>>4)*4+reg. swz: byte^=(row&7)<<4.
#include <hip/hip_runtime.h>
#include <hip/hip_bf16.h>

typedef __bf16 bf16x8 __attribute__((ext_vector_type(8)));
typedef __bf16 bf16x4 __attribute__((ext_vector_type(4)));
typedef float  f32x4  __attribute__((ext_vector_type(4)));

constexpr int Cc  = 512;
constexpr int HWn = 4096;
constexpr int Pn  = 2048;
constexpr int NC  = 256;
constexpr int Mdense = 16 * HWn;   // 65536
constexpr int Mout   = 16 * Pn;    // 32768
constexpr int BM   = 128;
constexpr int NTHR = 512;          // 8 waves: 4(M) x 2(N)

__device__ __forceinline__ int swz(int row, int byte_in_row) {
  return row * 128 + (byte_in_row ^ ((row & 7) << 4));
}
__device__ __forceinline__ f32x4 mfma16(bf16x8 a, bf16x8 b, f32x4 c) {
  return __builtin_amdgcn_mfma_f32_16x16x32_bf16(a, b, c, 0, 0, 0);
}

// ---------------------------------------------- k0: weights fp32 -> bf16
__global__ void k0_prep(const float* __restrict__ w1, const float* __restrict__ w2,
                        __bf16* __restrict__ w1b, __bf16* __restrict__ w2b) {
  int i = blockIdx.x * 256 + threadIdx.x;          // float4 id, 49152 total
  const float4 f = (i < 32768) ? ((const float4*)w1)[i] : ((const float4*)w2)[i - 32768];
  bf16x4 v; v[0] = (__bf16)f.x; v[1] = (__bf16)f.y; v[2] = (__bf16)f.z; v[3] = (__bf16)f.w;
  if (i < 32768) ((bf16x4*)w1b)[i] = v;
  else           ((bf16x4*)w2b)[i - 32768] = v;
}

// ---------------------------------------------- k1: dense MLP layer 1
__global__ __launch_bounds__(NTHR, 4)
void k1_dense(const float* __restrict__ feat, const __bf16* __restrict__ w1b,
              const float* __restrict__ b1, __bf16* __restrict__ h) {
  __shared__ __align__(16) char sA[BM * 128];   // 128 pos x 64 k bf16, swz
  __shared__ __align__(16) char sB[NC * 128];   // 256 n   x 64 k bf16, swz

  const int tid = threadIdx.x;
  const int m0  = blockIdx.x * BM;
  const int b   = m0 >> 12, hw0 = m0 & (HWn - 1);
  const int wid = tid >> 6, lane = tid & 63;
  const int wm = wid >> 1, wn = wid & 1;
  const int g = lane >> 4, ln = lane & 15;

  // A staging: thread owns channels c0..c0+3, positions p40*4..p40*4+3
  const int c0 = (tid & 15) * 4, p40 = tid >> 4;
  const float* aBase = feat + (((size_t)(b * Cc + c0)) << 12) + hw0 + p40 * 4;
  // B staging: thread owns rows nB+64r (r=0..3), 16B chunk c8
  const int nB = tid >> 3, c8 = tid & 7;
  const __bf16* bBase = w1b + (size_t)nB * Cc + c8 * 8;

  f32x4 acc[2][8];
  #pragma unroll
  for (int rt = 0; rt < 2; ++rt)
    #pragma unroll
    for (int ct = 0; ct < 8; ++ct) acc[rt][ct] = (f32x4){0.f, 0.f, 0.f, 0.f};

  f32x4 pA[4]; uint4 pB[4];
  #pragma unroll
  for (int r = 0; r < 4; ++r) pA[r] = *(const f32x4*)(aBase + (((size_t)r) << 12));
  #pragma unroll
  for (int r = 0; r < 4; ++r) pB[r] = *(const uint4*)(bBase + (size_t)(64 * r) * Cc);

  for (int kt = 0; kt < Cc / 64; ++kt) {
    // write A: in-register 4x4 transpose -> 4x ds_write_b64
    #pragma unroll
    for (int i = 0; i < 4; ++i) {
      bf16x4 v; v[0] = (__bf16)pA[0][i]; v[1] = (__bf16)pA[1][i];
                v[2] = (__bf16)pA[2][i]; v[3] = (__bf16)pA[3][i];
      *(uint2*)(sA + swz(p40 * 4 + i, c0 * 2)) = __builtin_bit_cast(uint2, v);
    }
    // write B: 4x b128 swizzled (rows nB, nB+64, nB+128, nB+192)
    #pragma unroll
    for (int r = 0; r < 4; ++r)
      *(uint4*)(sB + swz(nB + 64 * r, c8 * 16)) = pB[r];
    __syncthreads();
    // T14: issue next tile's global loads; in flight across the MFMA phase
    if (kt < Cc / 64 - 1) {
      const float*  a2 = aBase + (((size_t)((kt + 1) * 64)) << 12);
      const __bf16* b2 = bBase + (kt + 1) * 64;
      #pragma unroll
      for (int r = 0; r < 4; ++r) pA[r] = *(const f32x4*)(a2 + (((size_t)r) << 12));
      #pragma unroll
      for (int r = 0; r < 4; ++r) pB[r] = *(const uint4*)(b2 + (size_t)(64 * r) * Cc);
    }
    #pragma unroll
    for (int ki = 0; ki < 2; ++ki) {
      bf16x8 a0 = *(const bf16x8*)(sA + swz(wm * 32 + ln,      ki * 64 + g * 16));
      bf16x8 a1 = *(const bf16x8*)(sA + swz(wm * 32 + 16 + ln, ki * 64 + g * 16));
      #pragma unroll
      for (int ct = 0; ct < 8; ++ct) {
        bf16x8 bv = *(const bf16x8*)(sB + swz(wn * 128 + ct * 16 + ln, ki * 64 + g * 16));
        acc[0][ct] = mfma16(a0, bv, acc[0][ct]);
        acc[1][ct] = mfma16(a1, bv, acc[1][ct]);
      }
    }
    __syncthreads();
  }

  #pragma unroll
  for (int ct = 0; ct < 8; ++ct) {
    const int col = wn * 128 + ct * 16 + ln;
    const float bias = b1[col];
    #pragma unroll
    for (int rt = 0; rt < 2; ++rt)
      #pragma unroll
      for (int j = 0; j < 4; ++j) {
        int row = m0 + wm * 32 + rt * 16 + g * 4 + j;
        float v = acc[rt][ct][j] + bias;
        h[(size_t)row * NC + col] = (__bf16)(v > 0.f ? v : 0.f);
      }
  }
}

// ---------------------------------------------- k2: gather + layer 2 + L2norm
__global__ __launch_bounds__(NTHR, 4)
void k2_gather(const __bf16* __restrict__ h, const int* __restrict__ pid,
               const __bf16* __restrict__ w2b, const float* __restrict__ b2,
               float* __restrict__ out) {
  __shared__ __align__(16) char sA[BM * 128];
  __shared__ __align__(16) char sB[NC * 128];
  __shared__ int sRow[BM];
  __shared__ float sRS[BM][2];

  const int tid = threadIdx.x;
  const int m0  = blockIdx.x * BM;
  const int img = m0 >> 11;
  const int p0  = m0 & (Pn - 1);
  if (tid < BM) sRow[tid] = img * HWn + pid[p0 + tid];
  __syncthreads();

  const int wid = tid >> 6, lane = tid & 63;
  const int wm = wid >> 1, wn = wid & 1;
  const int g = lane >> 4, ln = lane & 15;

  // A: gathered h rows (512B each); thread owns (mmA = tid>>3, chunk c8)
  const int mmA = tid >> 3, c8 = tid & 7;
  // B: w2b rows nB+64r (r=0..3), chunk c8
  const int nB = mmA;
  const __bf16* bBase = w2b + (size_t)nB * NC + c8 * 8;
  const char* hb = (const char*)h;

  f32x4 acc[2][8];
  #pragma unroll
  for (int rt = 0; rt < 2; ++rt)
    #pragma unroll
    for (int ct = 0; ct < 8; ++ct) acc[rt][ct] = (f32x4){0.f, 0.f, 0.f, 0.f};

  uint4 qA[2], qB[4];
  #pragma unroll
  for (int r = 0; r < 2; ++r)
    qA[r] = *(const uint4*)(hb + (size_t)sRow[mmA + 64 * r] * 512 + c8 * 16);
  #pragma unroll
  for (int r = 0; r < 4; ++r) qB[r] = *(const uint4*)(bBase + (size_t)(64 * r) * NC);

  for (int kt = 0; kt < NC / 64; ++kt) {
    #pragma unroll
    for (int r = 0; r < 2; ++r)
      *(uint4*)(sA + swz(mmA + 64 * r, c8 * 16)) = qA[r];
    #pragma unroll
    for (int r = 0; r < 4; ++r)
      *(uint4*)(sB + swz(nB + 64 * r, c8 * 16)) = qB[r];
    __syncthreads();
    if (kt < NC / 64 - 1) {
      #pragma unroll
      for (int r = 0; r < 2; ++r)
        qA[r] = *(const uint4*)(hb + (size_t)sRow[mmA + 64 * r] * 512 + (kt + 1) * 128 + c8 * 16);
      const __bf16* b2p = bBase + (kt + 1) * 64;
      #pragma unroll
      for (int r = 0; r < 4; ++r) qB[r] = *(const uint4*)(b2p + (size_t)(64 * r) * NC);
    }
    #pragma unroll
    for (int ki = 0; ki < 2; ++ki) {
      bf16x8 a0 = *(const bf16x8*)(sA + swz(wm * 32 + ln,      ki * 64 + g * 16));
      bf16x8 a1 = *(const bf16x8*)(sA + swz(wm * 32 + 16 + ln, ki * 64 + g * 16));
      #pragma unroll
      for (int ct = 0; ct < 8; ++ct) {
        bf16x8 bv = *(const bf16x8*)(sB + swz(wn * 128 + ct * 16 + ln, ki * 64 + g * 16));
        acc[0][ct] = mfma16(a0, bv, acc[0][ct]);
        acc[1][ct] = mfma16(a1, bv, acc[1][ct]);
      }
    }
    __syncthreads();
  }

  float ss[2][4] = {{0.f,0.f,0.f,0.f},{0.f,0.f,0.f,0.f}};
  #pragma unroll
  for (int ct = 0; ct < 8; ++ct) {
    const int col = wn * 128 + ct * 16 + ln;
    const float bias = b2[col];
    #pragma unroll
    for (int rt = 0; rt < 2; ++rt)
      #pragma unroll
      for (int j = 0; j < 4; ++j) {
        float v = acc[rt][ct][j] + bias;
        acc[rt][ct][j] = v;
        ss[rt][j] += v * v;
      }
  }
  #pragma unroll
  for (int mk = 1; mk < 16; mk <<= 1)
    #pragma unroll
    for (int rt = 0; rt < 2; ++rt)
      #pragma unroll
      for (int j = 0; j < 4; ++j)
        ss[rt][j] += __shfl_xor(ss[rt][j], mk);
  if (ln == 0) {
    #pragma unroll
    for (int rt = 0; rt < 2; ++rt)
      #pragma unroll
      for (int j = 0; j < 4; ++j)
        sRS[wm * 32 + rt * 16 + g * 4 + j][wn] = ss[rt][j];
  }
  __syncthreads();
  float sc[2][4];
  #pragma unroll
  for (int rt = 0; rt < 2; ++rt)
    #pragma unroll
    for (int j = 0; j < 4; ++j) {
      int row = wm * 32 + rt * 16 + g * 4 + j;
      float t = sRS[row][0] + sRS[row][1];
      sc[rt][j] = 1.f / (sqrtf(t) + 1e-7f);
    }
  #pragma unroll
  for (int ct = 0; ct < 8; ++ct) {
    const int col = wn * 128 + ct * 16 + ln;
    #pragma unroll
    for (int rt = 0; rt < 2; ++rt)
      #pragma unroll
      for (int j = 0; j < 4; ++j) {
        int row = wm * 32 + rt * 16 + g * 4 + j;
        out[(size_t)(m0 + row) * NC + col] = acc[rt][ct][j] * sc[rt][j];
      }
  }
}

// ---------------------------------------------- launch
extern "C" void kernel_launch(void* const* d_in, const int* in_sizes, int n_in,
                              void* d_out, int out_size, void* d_ws, size_t ws_size,
                              hipStream_t stream) {
  const float* feat = (const float*)d_in[0];
  const int*   pid  = (const int*)d_in[1];
  const float* w1   = (const float*)d_in[2];
  const float* b1   = (const float*)d_in[3];
  const float* w2   = (const float*)d_in[4];
  const float* b2   = (const float*)d_in[5];
  float* out = (float*)d_out;

  char* ws = (char*)d_ws;
  __bf16* w1b = (__bf16*)ws;                       // 256 KiB
  __bf16* w2b = (__bf16*)(ws + 262144);            // 128 KiB
  __bf16* hbuf = (__bf16*)(ws + (1 << 20));        // 32 MiB dense h

  k0_prep <<<192, 256, 0, stream>>>(w1, w2, w1b, w2b);
  k1_dense<<<Mdense / BM, NTHR, 0, stream>>>(feat, w1b, b1, hbuf);
  k2_gather<<<Mout / BM, NTHR, 0, stream>>>(hbuf, pid, w2b, b2, out);
}